// Round 12
// baseline (323.056 us; speedup 1.0000x reference)
//
#include <hip/hip_runtime.h>

typedef unsigned short u16;
typedef __attribute__((ext_vector_type(8))) short bf16x8;
typedef __attribute__((ext_vector_type(4))) float f32x4;

constexpr int CH = 64;      // IN_CH == HID == 64
constexpr int NG = 64;      // graphs
constexpr int NC = 10;      // classes
constexpr int SHIFT = 9;    // bucket = 512 nodes
constexpr int BW = 1 << SHIFT;
constexpr int EPW = 8192;   // edges per workgroup in bucket pass

__device__ __forceinline__ void f4add(float4& a, const float4 v) {
    a.x += v.x; a.y += v.y; a.z += v.z; a.w += v.w;
}
__device__ __forceinline__ u16 f2bf(float f) {   // RNE f32->bf16
    unsigned u = __float_as_uint(f);
    u = (u + 0x7FFFu + ((u >> 16) & 1u)) >> 16;
    return (u16)u;
}
__device__ __forceinline__ void bfacc(float4& a, unsigned lo, unsigned hi) {
    a.x += __uint_as_float(lo << 16);
    a.y += __uint_as_float(lo & 0xFFFF0000u);
    a.z += __uint_as_float(hi << 16);
    a.w += __uint_as_float(hi & 0xFFFF0000u);
}

// ---- B1: bin edges by dst bucket; packed record = src | (dstLocal<<17) ----
__global__ __launch_bounds__(256) void k_bucket(const int* __restrict__ src,
                                                const int* __restrict__ dst,
                                                int* __restrict__ bcnt,
                                                int* __restrict__ bbuf,
                                                int nb, int cap, int n_edges)
{
    __shared__ int hist[256];
    __shared__ int cur[256];
    int t = threadIdx.x;
    int e0 = blockIdx.x * EPW;
    int e1 = min(e0 + EPW, n_edges);
    if (t < nb) hist[t] = 0;
    __syncthreads();
    for (int e = e0 + t; e < e1; e += 256)
        atomicAdd(&hist[dst[e] >> SHIFT], 1);
    __syncthreads();
    if (t < nb) cur[t] = atomicAdd(&bcnt[t], hist[t]);   // reserve range
    __syncthreads();
    for (int e = e0 + t; e < e1; e += 256) {
        int d = dst[e];
        int b = d >> SHIFT;
        int pos = atomicAdd(&cur[b], 1);
        if (pos < cap)
            bbuf[(size_t)b * cap + pos] = src[e] | ((d & (BW - 1)) << 17);
    }
}

// ---- B2: fused bucket-scan + per-bucket count/scan/place -------------------
__global__ __launch_bounds__(256) void k_build(const int* __restrict__ bbuf,
                                               const int* __restrict__ bcnt,
                                               int* __restrict__ rowptr,
                                               int* __restrict__ csr,
                                               int nb, int cap, int n)
{
    __shared__ int sc[256];
    __shared__ int hist[BW];
    __shared__ int cur[BW];
    __shared__ int psum[256];
    int b = blockIdx.x;
    int t = threadIdx.x;
    // ---- bucket-level exclusive scan (redundant per block) ----
    int v = (t < nb) ? min(bcnt[t], cap) : 0;
    sc[t] = v;
    __syncthreads();
    for (int off = 1; off < 256; off <<= 1) {
        int u = (t >= off) ? sc[t - off] : 0;
        __syncthreads();
        sc[t] += u;
        __syncthreads();
    }
    if (b == 0 && t == nb - 1) rowptr[n] = sc[t];   // grand total
    int cnt = min(bcnt[b], cap);
    int base = sc[b] - cnt;                         // exclusive prefix
    __syncthreads();
    // ---- local histogram + scan + place ----
    const int* mybuf = bbuf + (size_t)b * cap;
    hist[t] = 0; hist[t + 256] = 0;
    __syncthreads();
    for (int i = t; i < cnt; i += 256)
        atomicAdd(&hist[mybuf[i] >> 17], 1);
    __syncthreads();
    int h0 = hist[2 * t], h1 = hist[2 * t + 1];
    int ps = h0 + h1;
    psum[t] = ps;
    __syncthreads();
    for (int off = 1; off < 256; off <<= 1) {
        int u = (t >= off) ? psum[t - off] : 0;
        __syncthreads();
        psum[t] += u;
        __syncthreads();
    }
    int e0 = psum[t] - ps;                 // exclusive start of pair (2t,2t+1)
    int nodeBase = b * BW;
    cur[2 * t]     = base + e0;
    cur[2 * t + 1] = base + e0 + h0;
    if (nodeBase + 2 * t < n)     rowptr[nodeBase + 2 * t]     = base + e0;
    if (nodeBase + 2 * t + 1 < n) rowptr[nodeBase + 2 * t + 1] = base + e0 + h0;
    __syncthreads();
    for (int i = t; i < cnt; i += 256) {
        int vv = mybuf[i];
        int pos = atomicAdd(&cur[vv >> 17], 1);
        csr[pos] = vv & 0x1FFFF;
    }
}

// -------- MFMA dense: Y = in@Wrel^T (bf16), R = in@Wroot^T + b (bf16) ------
// One wave per 16-node group (2 groups/wave). Consistent k-permutation on
// A and B frags cancels vs HW slot order. C/D: col=lane&15, row=(lane>>4)*4+reg.
// Block 0 also zeroes Y row n (the gather tail's dummy row).
template<bool BF16IN>
__global__ __launch_bounds__(256) void k_xform_mfma(const void* in_,
                                                    const float* __restrict__ Wrel,
                                                    const float* __restrict__ Wroot,
                                                    const float* __restrict__ bias,
                                                    u16* __restrict__ Y,
                                                    u16* R, int n, int ngroups)
{
    if (blockIdx.x == 0 && threadIdx.x < 64)
        Y[(size_t)n * CH + threadIdx.x] = 0;     // zero dummy row

    int lane = threadIdx.x & 63;
    int lr = lane & 15;      // A-row / B-row(=out ch) / D-col
    int g  = lane >> 4;      // k-group

    bf16x8 wf[2][4][2];
    const float* Wm[2] = { Wrel, Wroot };
#pragma unroll
    for (int m = 0; m < 2; ++m)
#pragma unroll
        for (int t = 0; t < 4; ++t)
#pragma unroll
            for (int kt = 0; kt < 2; ++kt) {
                const float* p = Wm[m] + (16 * t + lr) * CH + 32 * kt + 8 * g;
                bf16x8 v;
#pragma unroll
                for (int j = 0; j < 8; ++j) v[j] = (short)f2bf(p[j]);
                wf[m][t][kt] = v;
            }
    float bvt[4];
#pragma unroll
    for (int t = 0; t < 4; ++t) bvt[t] = bias[16 * t + lr];

    int wid = blockIdx.x * 4 + (threadIdx.x >> 6);
#pragma unroll
    for (int gi = 0; gi < 2; ++gi) {
        int grp = wid * 2 + gi;
        if (grp >= ngroups) return;
        int gbase = grp * 16;
        int arow = gbase + lr;
        if (arow >= n) arow = n - 1;

        bf16x8 af[2];
#pragma unroll
        for (int kt = 0; kt < 2; ++kt) {
            if (BF16IN) {
                const u16* hp = (const u16*)in_ + (size_t)arow * CH + kt * 32 + 8 * g;
                af[kt] = *(const bf16x8*)hp;
            } else {
                const float* xp = (const float*)in_ + (size_t)arow * CH + kt * 32 + 8 * g;
                bf16x8 v;
#pragma unroll
                for (int j = 0; j < 8; ++j) v[j] = (short)f2bf(xp[j]);
                af[kt] = v;
            }
        }

        f32x4 z = { 0.f, 0.f, 0.f, 0.f };
        f32x4 aY[4] = { z, z, z, z };
        f32x4 aR[4] = { z, z, z, z };
#pragma unroll
        for (int kt = 0; kt < 2; ++kt)
#pragma unroll
            for (int t = 0; t < 4; ++t) {
                aY[t] = __builtin_amdgcn_mfma_f32_16x16x32_bf16(af[kt], wf[0][t][kt], aY[t], 0, 0, 0);
                aR[t] = __builtin_amdgcn_mfma_f32_16x16x32_bf16(af[kt], wf[1][t][kt], aR[t], 0, 0, 0);
            }

#pragma unroll
        for (int t = 0; t < 4; ++t)
#pragma unroll
            for (int r = 0; r < 4; ++r) {
                int node = gbase + 4 * g + r;
                if (node < n) {
                    Y[(size_t)node * CH + 16 * t + lr] = f2bf(aY[t][r]);
                    R[(size_t)node * CH + 16 * t + lr] = f2bf(aR[t][r] + bvt[t]);
                }
            }
    }
}

// -------- gather v6: 8 lanes x uint4 per row, 32-edge granule ---------------
// Whole wave per node (proven R5 shape); 8 lanes x 16B = full 128B bf16 row,
// 8 groups -> 8 rows per load instr, 32-edge granule. Poisson(16) degrees:
// ~99% of nodes finish in ONE clamped round (4 csr + 4 Y loads). Invalid
// slots select zero row n (L1-hot). Butterfly xor {8,16,32} over 8 floats.
// Chunked-contiguous nodes (rowptr e1->e0 reuse); RO prefetched.
template<bool POOL>
__global__ __launch_bounds__(256) void k_gather6(const u16* __restrict__ Y,
                                                 const int* __restrict__ rowptr,
                                                 const int* __restrict__ csr,
                                                 u16* RO,
                                                 const int* __restrict__ batch,
                                                 float* __restrict__ sums,
                                                 int n, int chunk)
{
    int lane = threadIdx.x & 63;
    int g8 = lane >> 3, rl = lane & 7;        // edge-slot group / row-lane
    int wid = blockIdx.x * 4 + (threadIdx.x >> 6);
    int nb = wid * chunk, ne = min(nb + chunk, n);
    if (nb >= n) return;
    float4 runLo = make_float4(0, 0, 0, 0), runHi = runLo;
    int gcur = -1;
    int e0 = rowptr[nb];
    for (int node = nb; node < ne; ++node) {
        int e1 = rowptr[node + 1];
        uint4 pr = *(const uint4*)(RO + (size_t)node * CH + rl * 8);
        float4 aLo = make_float4(0, 0, 0, 0), aHi = aLo, bLo = aLo, bHi = aLo;
        int e = e0;
        for (; e + 32 <= e1; e += 32) {
            int s0 = csr[e + g8],      s1 = csr[e + 8 + g8];
            int s2 = csr[e + 16 + g8], s3 = csr[e + 24 + g8];
            uint4 p0 = *(const uint4*)(Y + (size_t)s0 * CH + rl * 8);
            uint4 p1 = *(const uint4*)(Y + (size_t)s1 * CH + rl * 8);
            uint4 p2 = *(const uint4*)(Y + (size_t)s2 * CH + rl * 8);
            uint4 p3 = *(const uint4*)(Y + (size_t)s3 * CH + rl * 8);
            bfacc(aLo, p0.x, p0.y); bfacc(aHi, p0.z, p0.w);
            bfacc(bLo, p1.x, p1.y); bfacc(bHi, p1.z, p1.w);
            bfacc(aLo, p2.x, p2.y); bfacc(aHi, p2.z, p2.w);
            bfacc(bLo, p3.x, p3.y); bfacc(bHi, p3.z, p3.w);
        }
        if (e < e1) {   // one clamped round covers the <=31-edge tail
            int s0 = (e + g8      < e1) ? csr[e + g8]      : n;
            int s1 = (e + 8 + g8  < e1) ? csr[e + 8 + g8]  : n;
            int s2 = (e + 16 + g8 < e1) ? csr[e + 16 + g8] : n;
            int s3 = (e + 24 + g8 < e1) ? csr[e + 24 + g8] : n;
            uint4 p0 = *(const uint4*)(Y + (size_t)s0 * CH + rl * 8);
            uint4 p1 = *(const uint4*)(Y + (size_t)s1 * CH + rl * 8);
            uint4 p2 = *(const uint4*)(Y + (size_t)s2 * CH + rl * 8);
            uint4 p3 = *(const uint4*)(Y + (size_t)s3 * CH + rl * 8);
            bfacc(aLo, p0.x, p0.y); bfacc(aHi, p0.z, p0.w);
            bfacc(bLo, p1.x, p1.y); bfacc(bHi, p1.z, p1.w);
            bfacc(aLo, p2.x, p2.y); bfacc(aHi, p2.z, p2.w);
            bfacc(bLo, p3.x, p3.y); bfacc(bHi, p3.z, p3.w);
        }
        e0 = e1;
        f4add(aLo, bLo); f4add(aHi, bHi);
#pragma unroll
        for (int s = 8; s <= 32; s <<= 1) {
            aLo.x += __shfl_xor(aLo.x, s); aLo.y += __shfl_xor(aLo.y, s);
            aLo.z += __shfl_xor(aLo.z, s); aLo.w += __shfl_xor(aLo.w, s);
            aHi.x += __shfl_xor(aHi.x, s); aHi.y += __shfl_xor(aHi.y, s);
            aHi.z += __shfl_xor(aHi.z, s); aHi.w += __shfl_xor(aHi.w, s);
        }
        float4 rLo = make_float4(0, 0, 0, 0), rHi = rLo;
        bfacc(rLo, pr.x, pr.y); bfacc(rHi, pr.z, pr.w);
        float4 hLo, hHi;
        hLo.x = fmaxf(aLo.x + rLo.x, 0.f); hLo.y = fmaxf(aLo.y + rLo.y, 0.f);
        hLo.z = fmaxf(aLo.z + rLo.z, 0.f); hLo.w = fmaxf(aLo.w + rLo.w, 0.f);
        hHi.x = fmaxf(aHi.x + rHi.x, 0.f); hHi.y = fmaxf(aHi.y + rHi.y, 0.f);
        hHi.z = fmaxf(aHi.z + rHi.z, 0.f); hHi.w = fmaxf(aHi.w + rHi.w, 0.f);
        if (!POOL) {
            if (g8 == 0) {
                uint4 o;
                o.x = (unsigned)f2bf(hLo.x) | ((unsigned)f2bf(hLo.y) << 16);
                o.y = (unsigned)f2bf(hLo.z) | ((unsigned)f2bf(hLo.w) << 16);
                o.z = (unsigned)f2bf(hHi.x) | ((unsigned)f2bf(hHi.y) << 16);
                o.w = (unsigned)f2bf(hHi.z) | ((unsigned)f2bf(hHi.w) << 16);
                *(uint4*)(RO + (size_t)node * CH + rl * 8) = o;
            }
        } else {
            int g = batch[node];
            if (g != gcur) {
                if (gcur >= 0 && g8 == 0) {
                    float* s = sums + gcur * CH + rl * 8;
                    atomicAdd(s + 0, runLo.x); atomicAdd(s + 1, runLo.y);
                    atomicAdd(s + 2, runLo.z); atomicAdd(s + 3, runLo.w);
                    atomicAdd(s + 4, runHi.x); atomicAdd(s + 5, runHi.y);
                    atomicAdd(s + 6, runHi.z); atomicAdd(s + 7, runHi.w);
                }
                runLo = make_float4(0, 0, 0, 0); runHi = runLo;
                gcur = g;
            }
            f4add(runLo, hLo); f4add(runHi, hHi);
        }
    }
    if (POOL && gcur >= 0 && g8 == 0) {
        float* s = sums + gcur * CH + rl * 8;
        atomicAdd(s + 0, runLo.x); atomicAdd(s + 1, runLo.y);
        atomicAdd(s + 2, runLo.z); atomicAdd(s + 3, runLo.w);
        atomicAdd(s + 4, runHi.x); atomicAdd(s + 5, runHi.y);
        atomicAdd(s + 6, runHi.z); atomicAdd(s + 7, runHi.w);
    }
}

// -------- final head --------------------------------------------------------
__global__ void k_final(const float* __restrict__ sums,
                        const int* __restrict__ batch,
                        const float* __restrict__ Wlin,
                        const float* __restrict__ blin,
                        float* __restrict__ out, int n_nodes)
{
    int t = threadIdx.x;
    if (t >= NG * NC) return;
    int g = t / NC, c = t % NC;
    int lo = 0, hi = n_nodes;
    while (lo < hi) { int mid = (lo + hi) >> 1; if (batch[mid] < g) lo = mid + 1; else hi = mid; }
    int lb = lo;
    lo = 0; hi = n_nodes;
    while (lo < hi) { int mid = (lo + hi) >> 1; if (batch[mid] < g + 1) lo = mid + 1; else hi = mid; }
    int cnt = lo - lb;
    float inv = 1.0f / fmaxf((float)cnt, 1.0f);
    float acc = blin[c];
    for (int k = 0; k < CH; ++k)
        acc += sums[g * CH + k] * inv * Wlin[c * CH + k];
    out[g * NC + c] = acc;
}

extern "C" void kernel_launch(void* const* d_in, const int* in_sizes, int n_in,
                              void* d_out, int out_size, void* d_ws, size_t ws_size,
                              hipStream_t stream)
{
    const float* x      = (const float*)d_in[0];
    const int*   ei     = (const int*)d_in[1];
    const int*   batch  = (const int*)d_in[2];
    const float* W1rel  = (const float*)d_in[3];
    const float* W1root = (const float*)d_in[4];
    const float* b1     = (const float*)d_in[5];
    const float* W2rel  = (const float*)d_in[6];
    const float* W2root = (const float*)d_in[7];
    const float* b2     = (const float*)d_in[8];
    const float* Wlin   = (const float*)d_in[9];
    const float* blin   = (const float*)d_in[10];
    float* out = (float*)d_out;

    int n_nodes = in_sizes[0] / CH;
    int n_edges = in_sizes[1] / 2;
    const int* src = ei;
    const int* dst = ei + n_edges;

    int nb  = (n_nodes + BW - 1) >> SHIFT;          // buckets (<=256)
    int cap = n_edges / nb + 2048;                  // per-bucket capacity

    // workspace: Ybf(n+1 rows) | Rbf | rowptr | csr(+32 pad) | bbuf | bcnt | sums
    u16*   Ybf    = (u16*)d_ws;
    u16*   Rbf    = Ybf + (size_t)(n_nodes + 1) * CH;
    int*   rowptr = (int*)(Rbf + (size_t)n_nodes * CH);
    int*   csr    = rowptr + (n_nodes + 1);
    int*   bbuf   = csr + n_edges + 32;             // +32: tail overread pad
    int*   bcnt   = bbuf + (size_t)nb * cap;
    float* sums   = (float*)(bcnt + 256);

    // ---- build CSR (dst -> srcs) via bucketed counting sort ----
    hipMemsetAsync(bcnt, 0, 256 * sizeof(int), stream);
    int b1blocks = (n_edges + EPW - 1) / EPW;
    k_bucket<<<b1blocks, 256, 0, stream>>>(src, dst, bcnt, bbuf, nb, cap, n_edges);
    k_build<<<nb, 256, 0, stream>>>(bbuf, bcnt, rowptr, csr, nb, cap, n_nodes);

    int ngroups16 = (n_nodes + 15) / 16;
    int xblocks = (ngroups16 + 7) / 8;              // 4 waves x 2 groups

    int waves = 2048 * 4;
    int chunk = (n_nodes + waves - 1) / waves;

    // ---- layer 1 ----
    k_xform_mfma<false><<<xblocks, 256, 0, stream>>>(x, W1rel, W1root, b1,
                                                     Ybf, Rbf, n_nodes, ngroups16);
    k_gather6<false><<<2048, 256, 0, stream>>>(Ybf, rowptr, csr, Rbf,
                                               batch, sums, n_nodes, chunk);

    // ---- layer 2 ----
    k_xform_mfma<true><<<xblocks, 256, 0, stream>>>(Rbf, W2rel, W2root, b2,
                                                    Ybf, Rbf, n_nodes, ngroups16);
    hipMemsetAsync(sums, 0, NG * CH * sizeof(float), stream);
    k_gather6<true><<<2048, 256, 0, stream>>>(Ybf, rowptr, csr, Rbf,
                                              batch, sums, n_nodes, chunk);

    // ---- head ----
    k_final<<<1, NG * NC, 0, stream>>>(sums, batch, Wlin, blin, out, n_nodes);
}

// Round 13
// 212.311 us; speedup vs baseline: 1.5216x; 1.5216x over previous
//
#include <hip/hip_runtime.h>

typedef unsigned short u16;
typedef __attribute__((ext_vector_type(8))) short bf16x8;
typedef __attribute__((ext_vector_type(4))) float f32x4;

constexpr int CH = 64;      // IN_CH == HID == 64
constexpr int NG = 64;      // graphs
constexpr int NC = 10;      // classes
constexpr int SHIFT = 9;    // bucket = 512 nodes
constexpr int BW = 1 << SHIFT;
constexpr int EPW = 8192;   // edges per workgroup in bucket pass

__device__ __forceinline__ void f4add(float4& a, const float4 v) {
    a.x += v.x; a.y += v.y; a.z += v.z; a.w += v.w;
}
__device__ __forceinline__ u16 f2bf(float f) {   // RNE f32->bf16
    unsigned u = __float_as_uint(f);
    u = (u + 0x7FFFu + ((u >> 16) & 1u)) >> 16;
    return (u16)u;
}
__device__ __forceinline__ void bfacc(float4& a, unsigned lo, unsigned hi) {
    a.x += __uint_as_float(lo << 16);
    a.y += __uint_as_float(lo & 0xFFFF0000u);
    a.z += __uint_as_float(hi << 16);
    a.w += __uint_as_float(hi & 0xFFFF0000u);
}

// ---- bucket body: bin edges by dst bucket; record = src | (dstLocal<<17) ---
__device__ __forceinline__ void bucket_body(int bid,
                                            const int* __restrict__ src,
                                            const int* __restrict__ dst,
                                            int* __restrict__ bcnt,
                                            int* __restrict__ bbuf,
                                            int nb, int cap, int n_edges)
{
    __shared__ int hist[256];
    __shared__ int cur[256];
    int t = threadIdx.x;
    int e0 = bid * EPW;
    int e1 = min(e0 + EPW, n_edges);
    if (t < nb) hist[t] = 0;
    __syncthreads();
    for (int e = e0 + t; e < e1; e += 256)
        atomicAdd(&hist[dst[e] >> SHIFT], 1);
    __syncthreads();
    if (t < nb) cur[t] = atomicAdd(&bcnt[t], hist[t]);   // reserve range
    __syncthreads();
    for (int e = e0 + t; e < e1; e += 256) {
        int d = dst[e];
        int b = d >> SHIFT;
        int pos = atomicAdd(&cur[b], 1);
        if (pos < cap)
            bbuf[(size_t)b * cap + pos] = src[e] | ((d & (BW - 1)) << 17);
    }
}

// ---- MFMA xform body: Y = in@Wrel^T (bf16), R = in@Wroot^T + b (bf16) -----
// One wave per 16-node group (2 groups/wave). Consistent k-permutation on
// A and B frags cancels vs HW slot order. C/D: col=lane&15, row=(lane>>4)*4+reg.
template<bool BF16IN>
__device__ __forceinline__ void xform_body(int bid, const void* in_,
                                           const float* __restrict__ Wrel,
                                           const float* __restrict__ Wroot,
                                           const float* __restrict__ bias,
                                           u16* __restrict__ Y,
                                           u16* R, int n, int ngroups)
{
    if (bid == 0 && threadIdx.x < 64)
        Y[(size_t)n * CH + threadIdx.x] = 0;     // zero dummy row (gather tail)

    int lane = threadIdx.x & 63;
    int lr = lane & 15;      // A-row / B-row(=out ch) / D-col
    int g  = lane >> 4;      // k-group

    bf16x8 wf[2][4][2];
    const float* Wm[2] = { Wrel, Wroot };
#pragma unroll
    for (int m = 0; m < 2; ++m)
#pragma unroll
        for (int t = 0; t < 4; ++t)
#pragma unroll
            for (int kt = 0; kt < 2; ++kt) {
                const float* p = Wm[m] + (16 * t + lr) * CH + 32 * kt + 8 * g;
                bf16x8 v;
#pragma unroll
                for (int j = 0; j < 8; ++j) v[j] = (short)f2bf(p[j]);
                wf[m][t][kt] = v;
            }
    float bvt[4];
#pragma unroll
    for (int t = 0; t < 4; ++t) bvt[t] = bias[16 * t + lr];

    int wid = bid * 4 + (threadIdx.x >> 6);
#pragma unroll
    for (int gi = 0; gi < 2; ++gi) {
        int grp = wid * 2 + gi;
        if (grp >= ngroups) return;
        int gbase = grp * 16;
        int arow = gbase + lr;
        if (arow >= n) arow = n - 1;

        bf16x8 af[2];
#pragma unroll
        for (int kt = 0; kt < 2; ++kt) {
            if (BF16IN) {
                const u16* hp = (const u16*)in_ + (size_t)arow * CH + kt * 32 + 8 * g;
                af[kt] = *(const bf16x8*)hp;
            } else {
                const float* xp = (const float*)in_ + (size_t)arow * CH + kt * 32 + 8 * g;
                bf16x8 v;
#pragma unroll
                for (int j = 0; j < 8; ++j) v[j] = (short)f2bf(xp[j]);
                af[kt] = v;
            }
        }

        f32x4 z = { 0.f, 0.f, 0.f, 0.f };
        f32x4 aY[4] = { z, z, z, z };
        f32x4 aR[4] = { z, z, z, z };
#pragma unroll
        for (int kt = 0; kt < 2; ++kt)
#pragma unroll
            for (int t = 0; t < 4; ++t) {
                aY[t] = __builtin_amdgcn_mfma_f32_16x16x32_bf16(af[kt], wf[0][t][kt], aY[t], 0, 0, 0);
                aR[t] = __builtin_amdgcn_mfma_f32_16x16x32_bf16(af[kt], wf[1][t][kt], aR[t], 0, 0, 0);
            }

#pragma unroll
        for (int t = 0; t < 4; ++t)
#pragma unroll
            for (int r = 0; r < 4; ++r) {
                int node = gbase + 4 * g + r;
                if (node < n) {
                    Y[(size_t)node * CH + 16 * t + lr] = f2bf(aY[t][r]);
                    R[(size_t)node * CH + 16 * t + lr] = f2bf(aR[t][r] + bvt[t]);
                }
            }
    }
}

// ---- fused: bucket blocks [0,xoff) || layer-1 xform blocks [xoff,...) ------
__global__ __launch_bounds__(256) void k_bx(const int* __restrict__ src,
                                            const int* __restrict__ dst,
                                            int* __restrict__ bcnt,
                                            int* __restrict__ bbuf,
                                            int nb, int cap, int n_edges,
                                            const float* __restrict__ x,
                                            const float* __restrict__ Wrel,
                                            const float* __restrict__ Wroot,
                                            const float* __restrict__ bias,
                                            u16* __restrict__ Y,
                                            u16* R, int n, int ngroups, int xoff)
{
    if ((int)blockIdx.x < xoff)
        bucket_body(blockIdx.x, src, dst, bcnt, bbuf, nb, cap, n_edges);
    else
        xform_body<false>(blockIdx.x - xoff, x, Wrel, Wroot, bias, Y, R, n, ngroups);
}

// ---- standalone layer-2 xform ----------------------------------------------
__global__ __launch_bounds__(256) void k_xform2(const u16* in_,
                                                const float* __restrict__ Wrel,
                                                const float* __restrict__ Wroot,
                                                const float* __restrict__ bias,
                                                u16* __restrict__ Y,
                                                u16* R, int n, int ngroups)
{
    xform_body<true>(blockIdx.x, in_, Wrel, Wroot, bias, Y, R, n, ngroups);
}

// ---- B2: fused bucket-scan + per-bucket count/scan/place -------------------
__global__ __launch_bounds__(256) void k_build(const int* __restrict__ bbuf,
                                               const int* __restrict__ bcnt,
                                               int* __restrict__ rowptr,
                                               int* __restrict__ csr,
                                               int nb, int cap, int n)
{
    __shared__ int sc[256];
    __shared__ int hist[BW];
    __shared__ int cur[BW];
    __shared__ int psum[256];
    int b = blockIdx.x;
    int t = threadIdx.x;
    // ---- bucket-level exclusive scan (redundant per block) ----
    int v = (t < nb) ? min(bcnt[t], cap) : 0;
    sc[t] = v;
    __syncthreads();
    for (int off = 1; off < 256; off <<= 1) {
        int u = (t >= off) ? sc[t - off] : 0;
        __syncthreads();
        sc[t] += u;
        __syncthreads();
    }
    if (b == 0 && t == nb - 1) rowptr[n] = sc[t];   // grand total
    int cnt = min(bcnt[b], cap);
    int base = sc[b] - cnt;                         // exclusive prefix
    __syncthreads();
    // ---- local histogram + scan + place ----
    const int* mybuf = bbuf + (size_t)b * cap;
    hist[t] = 0; hist[t + 256] = 0;
    __syncthreads();
    for (int i = t; i < cnt; i += 256)
        atomicAdd(&hist[mybuf[i] >> 17], 1);
    __syncthreads();
    int h0 = hist[2 * t], h1 = hist[2 * t + 1];
    int ps = h0 + h1;
    psum[t] = ps;
    __syncthreads();
    for (int off = 1; off < 256; off <<= 1) {
        int u = (t >= off) ? psum[t - off] : 0;
        __syncthreads();
        psum[t] += u;
        __syncthreads();
    }
    int e0 = psum[t] - ps;                 // exclusive start of pair (2t,2t+1)
    int nodeBase = b * BW;
    cur[2 * t]     = base + e0;
    cur[2 * t + 1] = base + e0 + h0;
    if (nodeBase + 2 * t < n)     rowptr[nodeBase + 2 * t]     = base + e0;
    if (nodeBase + 2 * t + 1 < n) rowptr[nodeBase + 2 * t + 1] = base + e0 + h0;
    __syncthreads();
    for (int i = t; i < cnt; i += 256) {
        int vv = mybuf[i];
        int pos = atomicAdd(&cur[vv >> 17], 1);
        csr[pos] = vv & 0x1FFFF;
    }
}

// -------- gather v5 (PROVEN, unchanged): R5 main loop + clamped tail --------
template<bool POOL>
__global__ __launch_bounds__(256) void k_gather5(const u16* __restrict__ Y,
                                                 const int* __restrict__ rowptr,
                                                 const int* __restrict__ csr,
                                                 u16* RO,
                                                 const int* __restrict__ batch,
                                                 float* __restrict__ sums,
                                                 int n, int chunk)
{
    int lane = threadIdx.x & 63;
    int grp = lane >> 4, sub = lane & 15;
    int wid = blockIdx.x * 4 + (threadIdx.x >> 6);
    int nb = wid * chunk, ne = min(nb + chunk, n);
    if (nb >= n) return;
    float4 run = make_float4(0, 0, 0, 0);
    int gcur = -1;
    int e0 = rowptr[nb];
    for (int node = nb; node < ne; ++node) {
        int e1 = rowptr[node + 1];
        uint2 pr = *(const uint2*)(RO + (size_t)node * CH + sub * 4);
        float4 a0 = make_float4(0, 0, 0, 0), a1 = a0;
        int e = e0;
        for (; e + 16 <= e1; e += 16) {
            int s0 = csr[e + grp],      s1 = csr[e + 4 + grp];
            int s2 = csr[e + 8 + grp],  s3 = csr[e + 12 + grp];
            uint2 p0 = *(const uint2*)(Y + (size_t)s0 * CH + sub * 4);
            uint2 p1 = *(const uint2*)(Y + (size_t)s1 * CH + sub * 4);
            uint2 p2 = *(const uint2*)(Y + (size_t)s2 * CH + sub * 4);
            uint2 p3 = *(const uint2*)(Y + (size_t)s3 * CH + sub * 4);
            bfacc(a0, p0.x, p0.y); bfacc(a1, p1.x, p1.y);
            bfacc(a0, p2.x, p2.y); bfacc(a1, p3.x, p3.y);
        }
        if (e < e1) {   // one clamped round covers the <=15-edge tail
            int s0 = (e + grp      < e1) ? csr[e + grp]      : n;
            int s1 = (e + 4 + grp  < e1) ? csr[e + 4 + grp]  : n;
            int s2 = (e + 8 + grp  < e1) ? csr[e + 8 + grp]  : n;
            int s3 = (e + 12 + grp < e1) ? csr[e + 12 + grp] : n;
            uint2 p0 = *(const uint2*)(Y + (size_t)s0 * CH + sub * 4);
            uint2 p1 = *(const uint2*)(Y + (size_t)s1 * CH + sub * 4);
            uint2 p2 = *(const uint2*)(Y + (size_t)s2 * CH + sub * 4);
            uint2 p3 = *(const uint2*)(Y + (size_t)s3 * CH + sub * 4);
            bfacc(a0, p0.x, p0.y); bfacc(a1, p1.x, p1.y);
            bfacc(a0, p2.x, p2.y); bfacc(a1, p3.x, p3.y);
        }
        e0 = e1;
        f4add(a0, a1);
        a0.x += __shfl_xor(a0.x, 16); a0.y += __shfl_xor(a0.y, 16);
        a0.z += __shfl_xor(a0.z, 16); a0.w += __shfl_xor(a0.w, 16);
        a0.x += __shfl_xor(a0.x, 32); a0.y += __shfl_xor(a0.y, 32);
        a0.z += __shfl_xor(a0.z, 32); a0.w += __shfl_xor(a0.w, 32);
        float4 r = make_float4(0, 0, 0, 0);
        bfacc(r, pr.x, pr.y);
        float4 h;
        h.x = fmaxf(a0.x + r.x, 0.f); h.y = fmaxf(a0.y + r.y, 0.f);
        h.z = fmaxf(a0.z + r.z, 0.f); h.w = fmaxf(a0.w + r.w, 0.f);
        if (!POOL) {
            if (grp == 0) {
                uint2 o;
                o.x = (unsigned)f2bf(h.x) | ((unsigned)f2bf(h.y) << 16);
                o.y = (unsigned)f2bf(h.z) | ((unsigned)f2bf(h.w) << 16);
                *(uint2*)(RO + (size_t)node * CH + sub * 4) = o;
            }
        } else {
            int g = batch[node];
            if (g != gcur) {
                if (gcur >= 0 && grp == 0) {
                    float* s = sums + gcur * CH + sub * 4;
                    atomicAdd(s + 0, run.x); atomicAdd(s + 1, run.y);
                    atomicAdd(s + 2, run.z); atomicAdd(s + 3, run.w);
                }
                run = make_float4(0, 0, 0, 0);
                gcur = g;
            }
            f4add(run, h);
        }
    }
    if (POOL && gcur >= 0 && grp == 0) {
        float* s = sums + gcur * CH + sub * 4;
        atomicAdd(s + 0, run.x); atomicAdd(s + 1, run.y);
        atomicAdd(s + 2, run.z); atomicAdd(s + 3, run.w);
    }
}

// -------- final head: one block per graph, 64 lanes, shuffle-reduce ---------
__global__ __launch_bounds__(64) void k_final2(const float* __restrict__ sums,
                                               const int* __restrict__ batch,
                                               const float* __restrict__ Wlin,
                                               const float* __restrict__ blin,
                                               float* __restrict__ out, int n_nodes)
{
    int g = blockIdx.x;
    int l = threadIdx.x;
    int lo = 0, hi = n_nodes;
    while (lo < hi) { int mid = (lo + hi) >> 1; if (batch[mid] < g) lo = mid + 1; else hi = mid; }
    int lb = lo;
    lo = 0; hi = n_nodes;
    while (lo < hi) { int mid = (lo + hi) >> 1; if (batch[mid] < g + 1) lo = mid + 1; else hi = mid; }
    int cnt = lo - lb;
    float inv = 1.0f / fmaxf((float)cnt, 1.0f);
    float v = sums[g * CH + l] * inv;
#pragma unroll
    for (int c = 0; c < NC; ++c) {
        float p = v * Wlin[c * CH + l];
        p += __shfl_xor(p, 1);  p += __shfl_xor(p, 2);  p += __shfl_xor(p, 4);
        p += __shfl_xor(p, 8);  p += __shfl_xor(p, 16); p += __shfl_xor(p, 32);
        if (l == 0) out[g * NC + c] = p + blin[c];
    }
}

extern "C" void kernel_launch(void* const* d_in, const int* in_sizes, int n_in,
                              void* d_out, int out_size, void* d_ws, size_t ws_size,
                              hipStream_t stream)
{
    const float* x      = (const float*)d_in[0];
    const int*   ei     = (const int*)d_in[1];
    const int*   batch  = (const int*)d_in[2];
    const float* W1rel  = (const float*)d_in[3];
    const float* W1root = (const float*)d_in[4];
    const float* b1     = (const float*)d_in[5];
    const float* W2rel  = (const float*)d_in[6];
    const float* W2root = (const float*)d_in[7];
    const float* b2     = (const float*)d_in[8];
    const float* Wlin   = (const float*)d_in[9];
    const float* blin   = (const float*)d_in[10];
    float* out = (float*)d_out;

    int n_nodes = in_sizes[0] / CH;
    int n_edges = in_sizes[1] / 2;
    const int* src = ei;
    const int* dst = ei + n_edges;

    int nb  = (n_nodes + BW - 1) >> SHIFT;          // buckets (<=256)
    int cap = n_edges / nb + 2048;                  // per-bucket capacity

    // workspace: Ybf(n+1 rows) | Rbf | rowptr | csr(+32 pad) | bbuf | bcnt | sums
    u16*   Ybf    = (u16*)d_ws;
    u16*   Rbf    = Ybf + (size_t)(n_nodes + 1) * CH;
    int*   rowptr = (int*)(Rbf + (size_t)n_nodes * CH);
    int*   csr    = rowptr + (n_nodes + 1);
    int*   bbuf   = csr + n_edges + 32;             // +32: tail overread pad
    int*   bcnt   = bbuf + (size_t)nb * cap;
    float* sums   = (float*)(bcnt + 256);

    int ngroups16 = (n_nodes + 15) / 16;
    int xblocks = (ngroups16 + 7) / 8;              // 4 waves x 2 groups
    int b1blocks = (n_edges + EPW - 1) / EPW;

    int waves = 2048 * 4;
    int chunk = (n_nodes + waves - 1) / waves;

    // ---- fused: CSR bucket pass || layer-1 MFMA xform ----
    hipMemsetAsync(bcnt, 0, 256 * sizeof(int), stream);
    k_bx<<<b1blocks + xblocks, 256, 0, stream>>>(src, dst, bcnt, bbuf, nb, cap, n_edges,
                                                 x, W1rel, W1root, b1,
                                                 Ybf, Rbf, n_nodes, ngroups16, b1blocks);
    k_build<<<nb, 256, 0, stream>>>(bbuf, bcnt, rowptr, csr, nb, cap, n_nodes);

    // ---- layer 1 gather ----
    k_gather5<false><<<2048, 256, 0, stream>>>(Ybf, rowptr, csr, Rbf,
                                               batch, sums, n_nodes, chunk);

    // ---- layer 2 ----
    k_xform2<<<xblocks, 256, 0, stream>>>(Rbf, W2rel, W2root, b2,
                                          Ybf, Rbf, n_nodes, ngroups16);
    hipMemsetAsync(sums, 0, NG * CH * sizeof(float), stream);
    k_gather5<true><<<2048, 256, 0, stream>>>(Ybf, rowptr, csr, Rbf,
                                              batch, sums, n_nodes, chunk);

    // ---- head ----
    k_final2<<<NG, 64, 0, stream>>>(sums, batch, Wlin, blin, out, n_nodes);
}

// Round 14
// 206.494 us; speedup vs baseline: 1.5645x; 1.0282x over previous
//
#include <hip/hip_runtime.h>

typedef unsigned short u16;
typedef __attribute__((ext_vector_type(8))) short bf16x8;
typedef __attribute__((ext_vector_type(4))) float f32x4;

constexpr int CH = 64;      // IN_CH == HID == 64
constexpr int NG = 64;      // graphs
constexpr int NC = 10;      // classes
constexpr int SHIFT = 9;    // bucket = 512 nodes
constexpr int BW = 1 << SHIFT;
constexpr int EPW = 4096;   // edges per workgroup in bucket pass
constexpr int PT = EPW / 256;   // contiguous edges per thread (16)

__device__ __forceinline__ void f4add(float4& a, const float4 v) {
    a.x += v.x; a.y += v.y; a.z += v.z; a.w += v.w;
}
__device__ __forceinline__ u16 f2bf(float f) {   // RNE f32->bf16
    unsigned u = __float_as_uint(f);
    u = (u + 0x7FFFu + ((u >> 16) & 1u)) >> 16;
    return (u16)u;
}
__device__ __forceinline__ void bfacc(float4& a, unsigned lo, unsigned hi) {
    a.x += __uint_as_float(lo << 16);
    a.y += __uint_as_float(lo & 0xFFFF0000u);
    a.z += __uint_as_float(hi << 16);
    a.w += __uint_as_float(hi & 0xFFFF0000u);
}

// ---- bucket body v2: int4 edge reads, dst cached in regs across phases ----
// Each thread owns a contiguous PT(=16)-edge strip: 4 int4 loads of dst
// (phase 1, kept in regs), 4 int4 loads of src (phase 3). Record =
// src | (dstLocal<<17). Bucket-internal order changes vs scalar version --
// harmless (k_build re-sorts by dstLocal).
__device__ __forceinline__ void bucket_body(int bid,
                                            const int* __restrict__ src,
                                            const int* __restrict__ dst,
                                            int* __restrict__ bcnt,
                                            int* __restrict__ bbuf,
                                            int nb, int cap, int n_edges)
{
    __shared__ int hist[256];
    __shared__ int cur[256];
    int t = threadIdx.x;
    int e0 = bid * EPW;
    int e1 = min(e0 + EPW, n_edges);
    if (t < nb) hist[t] = 0;
    __syncthreads();
    int base = e0 + t * PT;
    bool full = (base + PT <= e1);
    int db[PT];
    if (full) {
        const int4* p = (const int4*)(dst + base);
#pragma unroll
        for (int j = 0; j < PT / 4; ++j) {
            int4 v = p[j];
            db[4 * j + 0] = v.x; db[4 * j + 1] = v.y;
            db[4 * j + 2] = v.z; db[4 * j + 3] = v.w;
        }
#pragma unroll
        for (int j = 0; j < PT; ++j) atomicAdd(&hist[db[j] >> SHIFT], 1);
    } else {
        for (int i = base; i < e1; ++i) atomicAdd(&hist[dst[i] >> SHIFT], 1);
    }
    __syncthreads();
    if (t < nb) cur[t] = atomicAdd(&bcnt[t], hist[t]);   // reserve range
    __syncthreads();
    if (full) {
        int sb[PT];
        const int4* p = (const int4*)(src + base);
#pragma unroll
        for (int j = 0; j < PT / 4; ++j) {
            int4 v = p[j];
            sb[4 * j + 0] = v.x; sb[4 * j + 1] = v.y;
            sb[4 * j + 2] = v.z; sb[4 * j + 3] = v.w;
        }
#pragma unroll
        for (int j = 0; j < PT; ++j) {
            int d = db[j];
            int b = d >> SHIFT;
            int pos = atomicAdd(&cur[b], 1);
            if (pos < cap)
                bbuf[(size_t)b * cap + pos] = sb[j] | ((d & (BW - 1)) << 17);
        }
    } else {
        for (int i = base; i < e1; ++i) {
            int d = dst[i];
            int b = d >> SHIFT;
            int pos = atomicAdd(&cur[b], 1);
            if (pos < cap)
                bbuf[(size_t)b * cap + pos] = src[i] | ((d & (BW - 1)) << 17);
        }
    }
}

// ---- MFMA xform body: Y = in@Wrel^T (bf16), R = in@Wroot^T + b (bf16) -----
// One wave per 16-node group (2 groups/wave). Consistent k-permutation on
// A and B frags cancels vs HW slot order. C/D: col=lane&15, row=(lane>>4)*4+reg.
template<bool BF16IN>
__device__ __forceinline__ void xform_body(int bid, const void* in_,
                                           const float* __restrict__ Wrel,
                                           const float* __restrict__ Wroot,
                                           const float* __restrict__ bias,
                                           u16* __restrict__ Y,
                                           u16* R, int n, int ngroups)
{
    if (bid == 0 && threadIdx.x < 64)
        Y[(size_t)n * CH + threadIdx.x] = 0;     // zero dummy row (gather tail)

    int lane = threadIdx.x & 63;
    int lr = lane & 15;      // A-row / B-row(=out ch) / D-col
    int g  = lane >> 4;      // k-group

    bf16x8 wf[2][4][2];
    const float* Wm[2] = { Wrel, Wroot };
#pragma unroll
    for (int m = 0; m < 2; ++m)
#pragma unroll
        for (int t = 0; t < 4; ++t)
#pragma unroll
            for (int kt = 0; kt < 2; ++kt) {
                const float* p = Wm[m] + (16 * t + lr) * CH + 32 * kt + 8 * g;
                bf16x8 v;
#pragma unroll
                for (int j = 0; j < 8; ++j) v[j] = (short)f2bf(p[j]);
                wf[m][t][kt] = v;
            }
    float bvt[4];
#pragma unroll
    for (int t = 0; t < 4; ++t) bvt[t] = bias[16 * t + lr];

    int wid = bid * 4 + (threadIdx.x >> 6);
#pragma unroll
    for (int gi = 0; gi < 2; ++gi) {
        int grp = wid * 2 + gi;
        if (grp >= ngroups) return;
        int gbase = grp * 16;
        int arow = gbase + lr;
        if (arow >= n) arow = n - 1;

        bf16x8 af[2];
#pragma unroll
        for (int kt = 0; kt < 2; ++kt) {
            if (BF16IN) {
                const u16* hp = (const u16*)in_ + (size_t)arow * CH + kt * 32 + 8 * g;
                af[kt] = *(const bf16x8*)hp;
            } else {
                const float* xp = (const float*)in_ + (size_t)arow * CH + kt * 32 + 8 * g;
                bf16x8 v;
#pragma unroll
                for (int j = 0; j < 8; ++j) v[j] = (short)f2bf(xp[j]);
                af[kt] = v;
            }
        }

        f32x4 z = { 0.f, 0.f, 0.f, 0.f };
        f32x4 aY[4] = { z, z, z, z };
        f32x4 aR[4] = { z, z, z, z };
#pragma unroll
        for (int kt = 0; kt < 2; ++kt)
#pragma unroll
            for (int t = 0; t < 4; ++t) {
                aY[t] = __builtin_amdgcn_mfma_f32_16x16x32_bf16(af[kt], wf[0][t][kt], aY[t], 0, 0, 0);
                aR[t] = __builtin_amdgcn_mfma_f32_16x16x32_bf16(af[kt], wf[1][t][kt], aR[t], 0, 0, 0);
            }

#pragma unroll
        for (int t = 0; t < 4; ++t)
#pragma unroll
            for (int r = 0; r < 4; ++r) {
                int node = gbase + 4 * g + r;
                if (node < n) {
                    Y[(size_t)node * CH + 16 * t + lr] = f2bf(aY[t][r]);
                    R[(size_t)node * CH + 16 * t + lr] = f2bf(aR[t][r] + bvt[t]);
                }
            }
    }
}

// ---- fused: bucket blocks [0,xoff) || layer-1 xform blocks [xoff,...) ------
__global__ __launch_bounds__(256) void k_bx(const int* __restrict__ src,
                                            const int* __restrict__ dst,
                                            int* __restrict__ bcnt,
                                            int* __restrict__ bbuf,
                                            int nb, int cap, int n_edges,
                                            const float* __restrict__ x,
                                            const float* __restrict__ Wrel,
                                            const float* __restrict__ Wroot,
                                            const float* __restrict__ bias,
                                            u16* __restrict__ Y,
                                            u16* R, int n, int ngroups, int xoff)
{
    if ((int)blockIdx.x < xoff)
        bucket_body(blockIdx.x, src, dst, bcnt, bbuf, nb, cap, n_edges);
    else
        xform_body<false>(blockIdx.x - xoff, x, Wrel, Wroot, bias, Y, R, n, ngroups);
}

// ---- standalone layer-2 xform ----------------------------------------------
__global__ __launch_bounds__(256) void k_xform2(const u16* in_,
                                                const float* __restrict__ Wrel,
                                                const float* __restrict__ Wroot,
                                                const float* __restrict__ bias,
                                                u16* __restrict__ Y,
                                                u16* R, int n, int ngroups)
{
    xform_body<true>(blockIdx.x, in_, Wrel, Wroot, bias, Y, R, n, ngroups);
}

// ---- B2: fused bucket-scan + per-bucket count/scan/place -------------------
__global__ __launch_bounds__(256) void k_build(const int* __restrict__ bbuf,
                                               const int* __restrict__ bcnt,
                                               int* __restrict__ rowptr,
                                               int* __restrict__ csr,
                                               int nb, int cap, int n)
{
    __shared__ int sc[256];
    __shared__ int hist[BW];
    __shared__ int cur[BW];
    __shared__ int psum[256];
    int b = blockIdx.x;
    int t = threadIdx.x;
    // ---- bucket-level exclusive scan (redundant per block) ----
    int v = (t < nb) ? min(bcnt[t], cap) : 0;
    sc[t] = v;
    __syncthreads();
    for (int off = 1; off < 256; off <<= 1) {
        int u = (t >= off) ? sc[t - off] : 0;
        __syncthreads();
        sc[t] += u;
        __syncthreads();
    }
    if (b == 0 && t == nb - 1) rowptr[n] = sc[t];   // grand total
    int cnt = min(bcnt[b], cap);
    int base = sc[b] - cnt;                         // exclusive prefix
    __syncthreads();
    // ---- local histogram + scan + place ----
    const int* mybuf = bbuf + (size_t)b * cap;
    hist[t] = 0; hist[t + 256] = 0;
    __syncthreads();
    for (int i = t; i < cnt; i += 256)
        atomicAdd(&hist[mybuf[i] >> 17], 1);
    __syncthreads();
    int h0 = hist[2 * t], h1 = hist[2 * t + 1];
    int ps = h0 + h1;
    psum[t] = ps;
    __syncthreads();
    for (int off = 1; off < 256; off <<= 1) {
        int u = (t >= off) ? psum[t - off] : 0;
        __syncthreads();
        psum[t] += u;
        __syncthreads();
    }
    int e0 = psum[t] - ps;                 // exclusive start of pair (2t,2t+1)
    int nodeBase = b * BW;
    cur[2 * t]     = base + e0;
    cur[2 * t + 1] = base + e0 + h0;
    if (nodeBase + 2 * t < n)     rowptr[nodeBase + 2 * t]     = base + e0;
    if (nodeBase + 2 * t + 1 < n) rowptr[nodeBase + 2 * t + 1] = base + e0 + h0;
    __syncthreads();
    for (int i = t; i < cnt; i += 256) {
        int vv = mybuf[i];
        int pos = atomicAdd(&cur[vv >> 17], 1);
        csr[pos] = vv & 0x1FFFF;
    }
}

// -------- gather v5 (PROVEN, unchanged): R5 main loop + clamped tail --------
template<bool POOL>
__global__ __launch_bounds__(256) void k_gather5(const u16* __restrict__ Y,
                                                 const int* __restrict__ rowptr,
                                                 const int* __restrict__ csr,
                                                 u16* RO,
                                                 const int* __restrict__ batch,
                                                 float* __restrict__ sums,
                                                 int n, int chunk)
{
    int lane = threadIdx.x & 63;
    int grp = lane >> 4, sub = lane & 15;
    int wid = blockIdx.x * 4 + (threadIdx.x >> 6);
    int nb = wid * chunk, ne = min(nb + chunk, n);
    if (nb >= n) return;
    float4 run = make_float4(0, 0, 0, 0);
    int gcur = -1;
    int e0 = rowptr[nb];
    for (int node = nb; node < ne; ++node) {
        int e1 = rowptr[node + 1];
        uint2 pr = *(const uint2*)(RO + (size_t)node * CH + sub * 4);
        float4 a0 = make_float4(0, 0, 0, 0), a1 = a0;
        int e = e0;
        for (; e + 16 <= e1; e += 16) {
            int s0 = csr[e + grp],      s1 = csr[e + 4 + grp];
            int s2 = csr[e + 8 + grp],  s3 = csr[e + 12 + grp];
            uint2 p0 = *(const uint2*)(Y + (size_t)s0 * CH + sub * 4);
            uint2 p1 = *(const uint2*)(Y + (size_t)s1 * CH + sub * 4);
            uint2 p2 = *(const uint2*)(Y + (size_t)s2 * CH + sub * 4);
            uint2 p3 = *(const uint2*)(Y + (size_t)s3 * CH + sub * 4);
            bfacc(a0, p0.x, p0.y); bfacc(a1, p1.x, p1.y);
            bfacc(a0, p2.x, p2.y); bfacc(a1, p3.x, p3.y);
        }
        if (e < e1) {   // one clamped round covers the <=15-edge tail
            int s0 = (e + grp      < e1) ? csr[e + grp]      : n;
            int s1 = (e + 4 + grp  < e1) ? csr[e + 4 + grp]  : n;
            int s2 = (e + 8 + grp  < e1) ? csr[e + 8 + grp]  : n;
            int s3 = (e + 12 + grp < e1) ? csr[e + 12 + grp] : n;
            uint2 p0 = *(const uint2*)(Y + (size_t)s0 * CH + sub * 4);
            uint2 p1 = *(const uint2*)(Y + (size_t)s1 * CH + sub * 4);
            uint2 p2 = *(const uint2*)(Y + (size_t)s2 * CH + sub * 4);
            uint2 p3 = *(const uint2*)(Y + (size_t)s3 * CH + sub * 4);
            bfacc(a0, p0.x, p0.y); bfacc(a1, p1.x, p1.y);
            bfacc(a0, p2.x, p2.y); bfacc(a1, p3.x, p3.y);
        }
        e0 = e1;
        f4add(a0, a1);
        a0.x += __shfl_xor(a0.x, 16); a0.y += __shfl_xor(a0.y, 16);
        a0.z += __shfl_xor(a0.z, 16); a0.w += __shfl_xor(a0.w, 16);
        a0.x += __shfl_xor(a0.x, 32); a0.y += __shfl_xor(a0.y, 32);
        a0.z += __shfl_xor(a0.z, 32); a0.w += __shfl_xor(a0.w, 32);
        float4 r = make_float4(0, 0, 0, 0);
        bfacc(r, pr.x, pr.y);
        float4 h;
        h.x = fmaxf(a0.x + r.x, 0.f); h.y = fmaxf(a0.y + r.y, 0.f);
        h.z = fmaxf(a0.z + r.z, 0.f); h.w = fmaxf(a0.w + r.w, 0.f);
        if (!POOL) {
            if (grp == 0) {
                uint2 o;
                o.x = (unsigned)f2bf(h.x) | ((unsigned)f2bf(h.y) << 16);
                o.y = (unsigned)f2bf(h.z) | ((unsigned)f2bf(h.w) << 16);
                *(uint2*)(RO + (size_t)node * CH + sub * 4) = o;
            }
        } else {
            int g = batch[node];
            if (g != gcur) {
                if (gcur >= 0 && grp == 0) {
                    float* s = sums + gcur * CH + sub * 4;
                    atomicAdd(s + 0, run.x); atomicAdd(s + 1, run.y);
                    atomicAdd(s + 2, run.z); atomicAdd(s + 3, run.w);
                }
                run = make_float4(0, 0, 0, 0);
                gcur = g;
            }
            f4add(run, h);
        }
    }
    if (POOL && gcur >= 0 && grp == 0) {
        float* s = sums + gcur * CH + sub * 4;
        atomicAdd(s + 0, run.x); atomicAdd(s + 1, run.y);
        atomicAdd(s + 2, run.z); atomicAdd(s + 3, run.w);
    }
}

// -------- final head: one block per graph, 64 lanes, shuffle-reduce ---------
__global__ __launch_bounds__(64) void k_final2(const float* __restrict__ sums,
                                               const int* __restrict__ batch,
                                               const float* __restrict__ Wlin,
                                               const float* __restrict__ blin,
                                               float* __restrict__ out, int n_nodes)
{
    int g = blockIdx.x;
    int l = threadIdx.x;
    int lo = 0, hi = n_nodes;
    while (lo < hi) { int mid = (lo + hi) >> 1; if (batch[mid] < g) lo = mid + 1; else hi = mid; }
    int lb = lo;
    lo = 0; hi = n_nodes;
    while (lo < hi) { int mid = (lo + hi) >> 1; if (batch[mid] < g + 1) lo = mid + 1; else hi = mid; }
    int cnt = lo - lb;
    float inv = 1.0f / fmaxf((float)cnt, 1.0f);
    float v = sums[g * CH + l] * inv;
#pragma unroll
    for (int c = 0; c < NC; ++c) {
        float p = v * Wlin[c * CH + l];
        p += __shfl_xor(p, 1);  p += __shfl_xor(p, 2);  p += __shfl_xor(p, 4);
        p += __shfl_xor(p, 8);  p += __shfl_xor(p, 16); p += __shfl_xor(p, 32);
        if (l == 0) out[g * NC + c] = p + blin[c];
    }
}

extern "C" void kernel_launch(void* const* d_in, const int* in_sizes, int n_in,
                              void* d_out, int out_size, void* d_ws, size_t ws_size,
                              hipStream_t stream)
{
    const float* x      = (const float*)d_in[0];
    const int*   ei     = (const int*)d_in[1];
    const int*   batch  = (const int*)d_in[2];
    const float* W1rel  = (const float*)d_in[3];
    const float* W1root = (const float*)d_in[4];
    const float* b1     = (const float*)d_in[5];
    const float* W2rel  = (const float*)d_in[6];
    const float* W2root = (const float*)d_in[7];
    const float* b2     = (const float*)d_in[8];
    const float* Wlin   = (const float*)d_in[9];
    const float* blin   = (const float*)d_in[10];
    float* out = (float*)d_out;

    int n_nodes = in_sizes[0] / CH;
    int n_edges = in_sizes[1] / 2;
    const int* src = ei;
    const int* dst = ei + n_edges;

    int nb  = (n_nodes + BW - 1) >> SHIFT;          // buckets (<=256)
    int cap = n_edges / nb + 2048;                  // per-bucket capacity

    // workspace: Ybf(n+1 rows) | Rbf | rowptr | csr(+32 pad) | bbuf | bcnt | sums
    u16*   Ybf    = (u16*)d_ws;
    u16*   Rbf    = Ybf + (size_t)(n_nodes + 1) * CH;
    int*   rowptr = (int*)(Rbf + (size_t)n_nodes * CH);
    int*   csr    = rowptr + (n_nodes + 1);
    int*   bbuf   = csr + n_edges + 32;             // +32: tail overread pad
    int*   bcnt   = bbuf + (size_t)nb * cap;
    float* sums   = (float*)(bcnt + 256);

    int ngroups16 = (n_nodes + 15) / 16;
    int xblocks = (ngroups16 + 7) / 8;              // 4 waves x 2 groups
    int b1blocks = (n_edges + EPW - 1) / EPW;

    int waves = 2048 * 4;
    int chunk = (n_nodes + waves - 1) / waves;

    // ---- fused: CSR bucket pass || layer-1 MFMA xform ----
    hipMemsetAsync(bcnt, 0, 256 * sizeof(int), stream);
    k_bx<<<b1blocks + xblocks, 256, 0, stream>>>(src, dst, bcnt, bbuf, nb, cap, n_edges,
                                                 x, W1rel, W1root, b1,
                                                 Ybf, Rbf, n_nodes, ngroups16, b1blocks);
    k_build<<<nb, 256, 0, stream>>>(bbuf, bcnt, rowptr, csr, nb, cap, n_nodes);

    // ---- layer 1 gather ----
    k_gather5<false><<<2048, 256, 0, stream>>>(Ybf, rowptr, csr, Rbf,
                                               batch, sums, n_nodes, chunk);

    // ---- layer 2 ----
    k_xform2<<<xblocks, 256, 0, stream>>>(Rbf, W2rel, W2root, b2,
                                          Ybf, Rbf, n_nodes, ngroups16);
    hipMemsetAsync(sums, 0, NG * CH * sizeof(float), stream);
    k_gather5<true><<<2048, 256, 0, stream>>>(Ybf, rowptr, csr, Rbf,
                                              batch, sums, n_nodes, chunk);

    // ---- head ----
    k_final2<<<NG, 64, 0, stream>>>(sums, batch, Wlin, blin, out, n_nodes);
}

// Round 15
// 198.340 us; speedup vs baseline: 1.6288x; 1.0411x over previous
//
#include <hip/hip_runtime.h>

typedef unsigned short u16;
typedef __attribute__((ext_vector_type(8))) short bf16x8;
typedef __attribute__((ext_vector_type(4))) float f32x4;

constexpr int CH = 64;      // IN_CH == HID == 64
constexpr int NG = 64;      // graphs
constexpr int NC = 10;      // classes
constexpr int SHIFT = 9;    // bucket = 512 nodes
constexpr int BW = 1 << SHIFT;
constexpr int EPW = 4096;   // edges per workgroup in bucket pass
constexpr int PT = EPW / 256;   // contiguous edges per thread (16)

__device__ __forceinline__ void f4add(float4& a, const float4 v) {
    a.x += v.x; a.y += v.y; a.z += v.z; a.w += v.w;
}
__device__ __forceinline__ u16 f2bf(float f) {   // RNE f32->bf16
    unsigned u = __float_as_uint(f);
    u = (u + 0x7FFFu + ((u >> 16) & 1u)) >> 16;
    return (u16)u;
}
__device__ __forceinline__ void bfacc(float4& a, unsigned lo, unsigned hi) {
    a.x += __uint_as_float(lo << 16);
    a.y += __uint_as_float(lo & 0xFFFF0000u);
    a.z += __uint_as_float(hi << 16);
    a.w += __uint_as_float(hi & 0xFFFF0000u);
}

// ---- bucket body v2 (PROVEN R14): int4 edge reads, dst cached in regs -----
__device__ __forceinline__ void bucket_body(int bid,
                                            const int* __restrict__ src,
                                            const int* __restrict__ dst,
                                            int* __restrict__ bcnt,
                                            int* __restrict__ bbuf,
                                            int nb, int cap, int n_edges)
{
    __shared__ int hist[256];
    __shared__ int cur[256];
    int t = threadIdx.x;
    int e0 = bid * EPW;
    int e1 = min(e0 + EPW, n_edges);
    if (t < nb) hist[t] = 0;
    __syncthreads();
    int base = e0 + t * PT;
    bool full = (base + PT <= e1);
    int db[PT];
    if (full) {
        const int4* p = (const int4*)(dst + base);
#pragma unroll
        for (int j = 0; j < PT / 4; ++j) {
            int4 v = p[j];
            db[4 * j + 0] = v.x; db[4 * j + 1] = v.y;
            db[4 * j + 2] = v.z; db[4 * j + 3] = v.w;
        }
#pragma unroll
        for (int j = 0; j < PT; ++j) atomicAdd(&hist[db[j] >> SHIFT], 1);
    } else {
        for (int i = base; i < e1; ++i) atomicAdd(&hist[dst[i] >> SHIFT], 1);
    }
    __syncthreads();
    if (t < nb) cur[t] = atomicAdd(&bcnt[t], hist[t]);   // reserve range
    __syncthreads();
    if (full) {
        int sb[PT];
        const int4* p = (const int4*)(src + base);
#pragma unroll
        for (int j = 0; j < PT / 4; ++j) {
            int4 v = p[j];
            sb[4 * j + 0] = v.x; sb[4 * j + 1] = v.y;
            sb[4 * j + 2] = v.z; sb[4 * j + 3] = v.w;
        }
#pragma unroll
        for (int j = 0; j < PT; ++j) {
            int d = db[j];
            int b = d >> SHIFT;
            int pos = atomicAdd(&cur[b], 1);
            if (pos < cap)
                bbuf[(size_t)b * cap + pos] = sb[j] | ((d & (BW - 1)) << 17);
        }
    } else {
        for (int i = base; i < e1; ++i) {
            int d = dst[i];
            int b = d >> SHIFT;
            int pos = atomicAdd(&cur[b], 1);
            if (pos < cap)
                bbuf[(size_t)b * cap + pos] = src[i] | ((d & (BW - 1)) << 17);
        }
    }
}

// ---- MFMA xform body (PROVEN): Y = in@Wrel^T ; R = in@Wroot^T + b ----------
// Group range [g0, gend); dummy-row zeroing gated on g0==0 && bid==0.
template<bool BF16IN>
__device__ __forceinline__ void xform_body(int bid, const void* in_,
                                           const float* __restrict__ Wrel,
                                           const float* __restrict__ Wroot,
                                           const float* __restrict__ bias,
                                           u16* __restrict__ Y,
                                           u16* R, int n, int g0, int gend)
{
    if (g0 == 0 && bid == 0 && threadIdx.x < 64)
        Y[(size_t)n * CH + threadIdx.x] = 0;     // zero dummy row (gather tail)

    int lane = threadIdx.x & 63;
    int lr = lane & 15;      // A-row / B-row(=out ch) / D-col
    int g  = lane >> 4;      // k-group

    bf16x8 wf[2][4][2];
    const float* Wm[2] = { Wrel, Wroot };
#pragma unroll
    for (int m = 0; m < 2; ++m)
#pragma unroll
        for (int t = 0; t < 4; ++t)
#pragma unroll
            for (int kt = 0; kt < 2; ++kt) {
                const float* p = Wm[m] + (16 * t + lr) * CH + 32 * kt + 8 * g;
                bf16x8 v;
#pragma unroll
                for (int j = 0; j < 8; ++j) v[j] = (short)f2bf(p[j]);
                wf[m][t][kt] = v;
            }
    float bvt[4];
#pragma unroll
    for (int t = 0; t < 4; ++t) bvt[t] = bias[16 * t + lr];

    int wid = bid * 4 + (threadIdx.x >> 6);
#pragma unroll
    for (int gi = 0; gi < 2; ++gi) {
        int grp = g0 + wid * 2 + gi;
        if (grp >= gend) return;
        int gbase = grp * 16;
        int arow = gbase + lr;
        if (arow >= n) arow = n - 1;

        bf16x8 af[2];
#pragma unroll
        for (int kt = 0; kt < 2; ++kt) {
            if (BF16IN) {
                const u16* hp = (const u16*)in_ + (size_t)arow * CH + kt * 32 + 8 * g;
                af[kt] = *(const bf16x8*)hp;
            } else {
                const float* xp = (const float*)in_ + (size_t)arow * CH + kt * 32 + 8 * g;
                bf16x8 v;
#pragma unroll
                for (int j = 0; j < 8; ++j) v[j] = (short)f2bf(xp[j]);
                af[kt] = v;
            }
        }

        f32x4 z = { 0.f, 0.f, 0.f, 0.f };
        f32x4 aY[4] = { z, z, z, z };
        f32x4 aR[4] = { z, z, z, z };
#pragma unroll
        for (int kt = 0; kt < 2; ++kt)
#pragma unroll
            for (int t = 0; t < 4; ++t) {
                aY[t] = __builtin_amdgcn_mfma_f32_16x16x32_bf16(af[kt], wf[0][t][kt], aY[t], 0, 0, 0);
                aR[t] = __builtin_amdgcn_mfma_f32_16x16x32_bf16(af[kt], wf[1][t][kt], aR[t], 0, 0, 0);
            }

#pragma unroll
        for (int t = 0; t < 4; ++t)
#pragma unroll
            for (int r = 0; r < 4; ++r) {
                int node = gbase + 4 * g + r;
                if (node < n) {
                    Y[(size_t)node * CH + 16 * t + lr] = f2bf(aY[t][r]);
                    R[(size_t)node * CH + 16 * t + lr] = f2bf(aR[t][r] + bvt[t]);
                }
            }
    }
}

// ---- build body (PROVEN R13/R14) + block 0 zeroes sums ---------------------
__device__ __forceinline__ void build_body(int b,
                                           const int* __restrict__ bbuf,
                                           const int* __restrict__ bcnt,
                                           int* __restrict__ rowptr,
                                           int* __restrict__ csr,
                                           float* __restrict__ sums,
                                           int nb, int cap, int n)
{
    __shared__ int sc[256];
    __shared__ int hist[BW];
    __shared__ int cur[BW];
    __shared__ int psum[256];
    int t = threadIdx.x;
    if (b == 0) {
        for (int i = t; i < NG * CH; i += 256) sums[i] = 0.f;
    }
    // ---- bucket-level exclusive scan (redundant per block) ----
    int v = (t < nb) ? min(bcnt[t], cap) : 0;
    sc[t] = v;
    __syncthreads();
    for (int off = 1; off < 256; off <<= 1) {
        int u = (t >= off) ? sc[t - off] : 0;
        __syncthreads();
        sc[t] += u;
        __syncthreads();
    }
    if (b == 0 && t == nb - 1) rowptr[n] = sc[t];   // grand total
    int cnt = min(bcnt[b], cap);
    int base = sc[b] - cnt;                         // exclusive prefix
    __syncthreads();
    // ---- local histogram + scan + place ----
    const int* mybuf = bbuf + (size_t)b * cap;
    hist[t] = 0; hist[t + 256] = 0;
    __syncthreads();
    for (int i = t; i < cnt; i += 256)
        atomicAdd(&hist[mybuf[i] >> 17], 1);
    __syncthreads();
    int h0 = hist[2 * t], h1 = hist[2 * t + 1];
    int ps = h0 + h1;
    psum[t] = ps;
    __syncthreads();
    for (int off = 1; off < 256; off <<= 1) {
        int u = (t >= off) ? psum[t - off] : 0;
        __syncthreads();
        psum[t] += u;
        __syncthreads();
    }
    int e0 = psum[t] - ps;                 // exclusive start of pair (2t,2t+1)
    int nodeBase = b * BW;
    cur[2 * t]     = base + e0;
    cur[2 * t + 1] = base + e0 + h0;
    if (nodeBase + 2 * t < n)     rowptr[nodeBase + 2 * t]     = base + e0;
    if (nodeBase + 2 * t + 1 < n) rowptr[nodeBase + 2 * t + 1] = base + e0 + h0;
    __syncthreads();
    for (int i = t; i < cnt; i += 256) {
        int vv = mybuf[i];
        int pos = atomicAdd(&cur[vv >> 17], 1);
        csr[pos] = vv & 0x1FFFF;
    }
}

// ---- K1: bucket blocks [0,xoff) || xform1 groups [0, gA) -------------------
__global__ __launch_bounds__(256) void k_b1x(const int* __restrict__ src,
                                             const int* __restrict__ dst,
                                             int* __restrict__ bcnt,
                                             int* __restrict__ bbuf,
                                             int nb, int cap, int n_edges,
                                             const float* __restrict__ x,
                                             const float* __restrict__ Wrel,
                                             const float* __restrict__ Wroot,
                                             const float* __restrict__ bias,
                                             u16* __restrict__ Y,
                                             u16* R, int n, int gA, int xoff)
{
    if ((int)blockIdx.x < xoff)
        bucket_body(blockIdx.x, src, dst, bcnt, bbuf, nb, cap, n_edges);
    else
        xform_body<false>(blockIdx.x - xoff, x, Wrel, Wroot, bias, Y, R, n, 0, gA);
}

// ---- K2: build blocks [0,nb) || xform1 groups [gA, ngroups) ----------------
__global__ __launch_bounds__(256) void k_b2x(const int* __restrict__ bbuf,
                                             const int* __restrict__ bcnt,
                                             int* __restrict__ rowptr,
                                             int* __restrict__ csr,
                                             float* __restrict__ sums,
                                             int nb, int cap,
                                             const float* __restrict__ x,
                                             const float* __restrict__ Wrel,
                                             const float* __restrict__ Wroot,
                                             const float* __restrict__ bias,
                                             u16* __restrict__ Y,
                                             u16* R, int n, int gA, int gend)
{
    if ((int)blockIdx.x < nb)
        build_body(blockIdx.x, bbuf, bcnt, rowptr, csr, sums, nb, cap, n);
    else
        xform_body<false>(blockIdx.x - nb, x, Wrel, Wroot, bias, Y, R, n, gA, gend);
}

// ---- standalone layer-2 xform ----------------------------------------------
__global__ __launch_bounds__(256) void k_xform2(const u16* in_,
                                                const float* __restrict__ Wrel,
                                                const float* __restrict__ Wroot,
                                                const float* __restrict__ bias,
                                                u16* __restrict__ Y,
                                                u16* R, int n, int ngroups)
{
    xform_body<true>(blockIdx.x, in_, Wrel, Wroot, bias, Y, R, n, 0, ngroups);
}

// -------- gather v5 (PROVEN, byte-identical to R14) --------------------------
template<bool POOL>
__global__ __launch_bounds__(256) void k_gather5(const u16* __restrict__ Y,
                                                 const int* __restrict__ rowptr,
                                                 const int* __restrict__ csr,
                                                 u16* RO,
                                                 const int* __restrict__ batch,
                                                 float* __restrict__ sums,
                                                 int n, int chunk)
{
    int lane = threadIdx.x & 63;
    int grp = lane >> 4, sub = lane & 15;
    int wid = blockIdx.x * 4 + (threadIdx.x >> 6);
    int nb = wid * chunk, ne = min(nb + chunk, n);
    if (nb >= n) return;
    float4 run = make_float4(0, 0, 0, 0);
    int gcur = -1;
    int e0 = rowptr[nb];
    for (int node = nb; node < ne; ++node) {
        int e1 = rowptr[node + 1];
        uint2 pr = *(const uint2*)(RO + (size_t)node * CH + sub * 4);
        float4 a0 = make_float4(0, 0, 0, 0), a1 = a0;
        int e = e0;
        for (; e + 16 <= e1; e += 16) {
            int s0 = csr[e + grp],      s1 = csr[e + 4 + grp];
            int s2 = csr[e + 8 + grp],  s3 = csr[e + 12 + grp];
            uint2 p0 = *(const uint2*)(Y + (size_t)s0 * CH + sub * 4);
            uint2 p1 = *(const uint2*)(Y + (size_t)s1 * CH + sub * 4);
            uint2 p2 = *(const uint2*)(Y + (size_t)s2 * CH + sub * 4);
            uint2 p3 = *(const uint2*)(Y + (size_t)s3 * CH + sub * 4);
            bfacc(a0, p0.x, p0.y); bfacc(a1, p1.x, p1.y);
            bfacc(a0, p2.x, p2.y); bfacc(a1, p3.x, p3.y);
        }
        if (e < e1) {   // one clamped round covers the <=15-edge tail
            int s0 = (e + grp      < e1) ? csr[e + grp]      : n;
            int s1 = (e + 4 + grp  < e1) ? csr[e + 4 + grp]  : n;
            int s2 = (e + 8 + grp  < e1) ? csr[e + 8 + grp]  : n;
            int s3 = (e + 12 + grp < e1) ? csr[e + 12 + grp] : n;
            uint2 p0 = *(const uint2*)(Y + (size_t)s0 * CH + sub * 4);
            uint2 p1 = *(const uint2*)(Y + (size_t)s1 * CH + sub * 4);
            uint2 p2 = *(const uint2*)(Y + (size_t)s2 * CH + sub * 4);
            uint2 p3 = *(const uint2*)(Y + (size_t)s3 * CH + sub * 4);
            bfacc(a0, p0.x, p0.y); bfacc(a1, p1.x, p1.y);
            bfacc(a0, p2.x, p2.y); bfacc(a1, p3.x, p3.y);
        }
        e0 = e1;
        f4add(a0, a1);
        a0.x += __shfl_xor(a0.x, 16); a0.y += __shfl_xor(a0.y, 16);
        a0.z += __shfl_xor(a0.z, 16); a0.w += __shfl_xor(a0.w, 16);
        a0.x += __shfl_xor(a0.x, 32); a0.y += __shfl_xor(a0.y, 32);
        a0.z += __shfl_xor(a0.z, 32); a0.w += __shfl_xor(a0.w, 32);
        float4 r = make_float4(0, 0, 0, 0);
        bfacc(r, pr.x, pr.y);
        float4 h;
        h.x = fmaxf(a0.x + r.x, 0.f); h.y = fmaxf(a0.y + r.y, 0.f);
        h.z = fmaxf(a0.z + r.z, 0.f); h.w = fmaxf(a0.w + r.w, 0.f);
        if (!POOL) {
            if (grp == 0) {
                uint2 o;
                o.x = (unsigned)f2bf(h.x) | ((unsigned)f2bf(h.y) << 16);
                o.y = (unsigned)f2bf(h.z) | ((unsigned)f2bf(h.w) << 16);
                *(uint2*)(RO + (size_t)node * CH + sub * 4) = o;
            }
        } else {
            int g = batch[node];
            if (g != gcur) {
                if (gcur >= 0 && grp == 0) {
                    float* s = sums + gcur * CH + sub * 4;
                    atomicAdd(s + 0, run.x); atomicAdd(s + 1, run.y);
                    atomicAdd(s + 2, run.z); atomicAdd(s + 3, run.w);
                }
                run = make_float4(0, 0, 0, 0);
                gcur = g;
            }
            f4add(run, h);
        }
    }
    if (POOL && gcur >= 0 && grp == 0) {
        float* s = sums + gcur * CH + sub * 4;
        atomicAdd(s + 0, run.x); atomicAdd(s + 1, run.y);
        atomicAdd(s + 2, run.z); atomicAdd(s + 3, run.w);
    }
}

// -------- final head: one block per graph, 64 lanes, shuffle-reduce ---------
__global__ __launch_bounds__(64) void k_final2(const float* __restrict__ sums,
                                               const int* __restrict__ batch,
                                               const float* __restrict__ Wlin,
                                               const float* __restrict__ blin,
                                               float* __restrict__ out, int n_nodes)
{
    int g = blockIdx.x;
    int l = threadIdx.x;
    int lo = 0, hi = n_nodes;
    while (lo < hi) { int mid = (lo + hi) >> 1; if (batch[mid] < g) lo = mid + 1; else hi = mid; }
    int lb = lo;
    lo = 0; hi = n_nodes;
    while (lo < hi) { int mid = (lo + hi) >> 1; if (batch[mid] < g + 1) lo = mid + 1; else hi = mid; }
    int cnt = lo - lb;
    float inv = 1.0f / fmaxf((float)cnt, 1.0f);
    float v = sums[g * CH + l] * inv;
#pragma unroll
    for (int c = 0; c < NC; ++c) {
        float p = v * Wlin[c * CH + l];
        p += __shfl_xor(p, 1);  p += __shfl_xor(p, 2);  p += __shfl_xor(p, 4);
        p += __shfl_xor(p, 8);  p += __shfl_xor(p, 16); p += __shfl_xor(p, 32);
        if (l == 0) out[g * NC + c] = p + blin[c];
    }
}

extern "C" void kernel_launch(void* const* d_in, const int* in_sizes, int n_in,
                              void* d_out, int out_size, void* d_ws, size_t ws_size,
                              hipStream_t stream)
{
    const float* x      = (const float*)d_in[0];
    const int*   ei     = (const int*)d_in[1];
    const int*   batch  = (const int*)d_in[2];
    const float* W1rel  = (const float*)d_in[3];
    const float* W1root = (const float*)d_in[4];
    const float* b1     = (const float*)d_in[5];
    const float* W2rel  = (const float*)d_in[6];
    const float* W2root = (const float*)d_in[7];
    const float* b2     = (const float*)d_in[8];
    const float* Wlin   = (const float*)d_in[9];
    const float* blin   = (const float*)d_in[10];
    float* out = (float*)d_out;

    int n_nodes = in_sizes[0] / CH;
    int n_edges = in_sizes[1] / 2;
    const int* src = ei;
    const int* dst = ei + n_edges;

    int nb  = (n_nodes + BW - 1) >> SHIFT;          // buckets (<=256)
    int cap = n_edges / nb + 2048;                  // per-bucket capacity

    // workspace: Ybf(n+1 rows) | Rbf | rowptr | csr(+32 pad) | bbuf | bcnt | sums
    u16*   Ybf    = (u16*)d_ws;
    u16*   Rbf    = Ybf + (size_t)(n_nodes + 1) * CH;
    int*   rowptr = (int*)(Rbf + (size_t)n_nodes * CH);
    int*   csr    = rowptr + (n_nodes + 1);
    int*   bbuf   = csr + n_edges + 32;             // +32: tail overread pad
    int*   bcnt   = bbuf + (size_t)nb * cap;
    float* sums   = (float*)(bcnt + 256);

    int ngroups16 = (n_nodes + 15) / 16;
    int xblocks = (ngroups16 + 7) / 8;              // 4 waves x 2 groups
    int b1blocks = (n_edges + EPW - 1) / EPW;

    // split xform1 60/40 across the two CSR phases
    int xfA = xblocks * 3 / 5;
    if (xfA < 1) xfA = 1;
    int gA = xfA * 8;
    if (gA > ngroups16) { gA = ngroups16; xfA = (gA + 7) / 8; }
    int xfB = (ngroups16 - gA + 7) / 8;

    int waves = 2048 * 4;
    int chunk = (n_nodes + waves - 1) / waves;

    // ---- K1: CSR bucket pass || layer-1 xform part A ----
    hipMemsetAsync(bcnt, 0, 256 * sizeof(int), stream);
    k_b1x<<<b1blocks + xfA, 256, 0, stream>>>(src, dst, bcnt, bbuf, nb, cap, n_edges,
                                              x, W1rel, W1root, b1,
                                              Ybf, Rbf, n_nodes, gA, b1blocks);
    // ---- K2: CSR build || layer-1 xform part B (also zeroes sums) ----
    k_b2x<<<nb + xfB, 256, 0, stream>>>(bbuf, bcnt, rowptr, csr, sums, nb, cap,
                                        x, W1rel, W1root, b1,
                                        Ybf, Rbf, n_nodes, gA, ngroups16);

    // ---- layer 1 gather ----
    k_gather5<false><<<2048, 256, 0, stream>>>(Ybf, rowptr, csr, Rbf,
                                               batch, sums, n_nodes, chunk);

    // ---- layer 2 ----
    k_xform2<<<xblocks, 256, 0, stream>>>(Rbf, W2rel, W2root, b2,
                                          Ybf, Rbf, n_nodes, ngroups16);
    k_gather5<true><<<2048, 256, 0, stream>>>(Ybf, rowptr, csr, Rbf,
                                              batch, sums, n_nodes, chunk);

    // ---- head ----
    k_final2<<<NG, 64, 0, stream>>>(sums, batch, Wlin, blin, out, n_nodes);
}